// Round 6
// baseline (85.145 us; speedup 1.0000x reference)
//
#include <hip/hip_runtime.h>

#define BB 2
#define LL 24
#define RR 8
#define CC 32
#define HH 48
#define WF 49
#define HW (HH*WF)            // 2352
#define ASLAB (RR*CC*WF)      // 12544  (A elements per (b,l))
#define SLAB (RR*CC*HH*WF)    // 602112 (u elements per (b,l))
#define OUT_HALF (BB*LL*SLAB) // 28901376
#define NCH (BB*SLAB)         // 1204224 independent chains
#define NTH2 (NCH/2)          // 602112 threads (2 consecutive chains each)

typedef float fvec2 __attribute__((ext_vector_type(2)));

__global__ __launch_bounds__(256) void a_kernel(const float* __restrict__ nu,
                                                const float* __restrict__ th,
                                                const float* __restrict__ dts,
                                                float* __restrict__ Ar,
                                                float* __restrict__ Ai) {
    int i = blockIdx.x * 256 + threadIdx.x;
    if (i >= BB * LL * ASLAB) return;
    int bl = i / ASLAB;             // b*L + l
    float dt = dts[bl];
    float decay = expf(-nu[i] * dt);
    float s, c;
    sincosf(th[i] * dt, &s, &c);
    Ar[i] = decay * c;
    Ai[i] = decay * s;
}

__device__ __forceinline__ void ntstore2(float* p, float a, float b) {
    fvec2 v = {a, b};
    __builtin_nontemporal_store(v, reinterpret_cast<fvec2*>(p));
}

__global__ __launch_bounds__(256) void scan_kernel(const float* __restrict__ ur,
                                                   const float* __restrict__ ui,
                                                   const float* __restrict__ Ar,
                                                   const float* __restrict__ Ai,
                                                   float* __restrict__ out) {
    int t = blockIdx.x * 256 + threadIdx.x;   // 0 .. NTH2-1 (exact grid)
    int c2 = t * 2;                           // first of 2 consecutive chains
    int b = c2 / SLAB;
    int rest = c2 - b * SLAB;                 // even, < SLAB
    int rc = rest / HW;                       // r*C + c   (A group)
    int hw = rest - rc * HW;                  // h*WF + w; hw+1 < HW since HW%2==0
    int w0 = hw % WF;

    int a_off[2];
    #pragma unroll
    for (int j = 0; j < 2; ++j) {
        int wj = w0 + j; if (wj >= WF) wj -= WF;   // w wraps within same rc
        a_off[j] = rc * WF + wj;
    }

    float hr[2] = {0.f, 0.f};
    float hi[2] = {0.f, 0.f};

    // ---- prologue: load l = 0 ----
    int base0 = b * LL * SLAB + rest;
    int ab0 = b * LL * ASLAB;
    fvec2 cxr = *reinterpret_cast<const fvec2*>(ur + base0);
    fvec2 cxi = *reinterpret_cast<const fvec2*>(ui + base0);
    float car[2], cai[2];
    #pragma unroll
    for (int j = 0; j < 2; ++j) {
        car[j] = Ar[ab0 + a_off[j]];
        cai[j] = Ai[ab0 + a_off[j]];
    }

    #pragma unroll
    for (int l = 0; l < LL; ++l) {
        int bl = b * LL + l;
        int base = bl * SLAB + rest;

        // ---- prefetch l+1 ----
        fvec2 nxr, nxi;
        float nar[2], nai[2];
        if (l + 1 < LL) {
            int nb = base + SLAB;
            nxr = *reinterpret_cast<const fvec2*>(ur + nb);
            nxi = *reinterpret_cast<const fvec2*>(ui + nb);
            int ab = (bl + 1) * ASLAB;
            #pragma unroll
            for (int j = 0; j < 2; ++j) {
                nar[j] = Ar[ab + a_off[j]];
                nai[j] = Ai[ab + a_off[j]];
            }
        }

        // ---- recurrence ----
        float xrv[2] = {cxr.x, cxr.y};
        float xiv[2] = {cxi.x, cxi.y};
        #pragma unroll
        for (int j = 0; j < 2; ++j) {
            float nr = car[j] * hr[j] - cai[j] * hi[j] + xrv[j];
            float ni = car[j] * hi[j] + cai[j] * hr[j] + xiv[j];
            hr[j] = nr; hi[j] = ni;
        }

        ntstore2(out + base,            hr[0], hr[1]);
        ntstore2(out + OUT_HALF + base, hi[0], hi[1]);

        // ---- rotate ----
        if (l + 1 < LL) {
            cxr = nxr; cxi = nxi;
            #pragma unroll
            for (int j = 0; j < 2; ++j) { car[j] = nar[j]; cai[j] = nai[j]; }
        }
    }
}

// Fallback (no workspace): recompute A inline per iteration.
__global__ __launch_bounds__(256) void scan_kernel_nows(const float* __restrict__ ur,
                                                        const float* __restrict__ ui,
                                                        const float* __restrict__ nu,
                                                        const float* __restrict__ th,
                                                        const float* __restrict__ dts,
                                                        float* __restrict__ out) {
    int t = blockIdx.x * 256 + threadIdx.x;
    int c2 = t * 2;
    int b = c2 / SLAB;
    int rest = c2 - b * SLAB;
    int rc = rest / HW;
    int hw = rest - rc * HW;
    int w0 = hw % WF;

    int a_off[2];
    #pragma unroll
    for (int j = 0; j < 2; ++j) {
        int wj = w0 + j; if (wj >= WF) wj -= WF;
        a_off[j] = rc * WF + wj;
    }

    float hr[2] = {0.f, 0.f};
    float hi[2] = {0.f, 0.f};

    for (int l = 0; l < LL; ++l) {
        int bl = b * LL + l;
        int base = bl * SLAB + rest;
        fvec2 xr = *reinterpret_cast<const fvec2*>(ur + base);
        fvec2 xi = *reinterpret_cast<const fvec2*>(ui + base);
        int ab = bl * ASLAB;
        float dt = dts[bl];
        float ar[2], ai[2];
        #pragma unroll
        for (int j = 0; j < 2; ++j) {
            float d = __expf(-nu[ab + a_off[j]] * dt);
            float s, c;
            __sincosf(th[ab + a_off[j]] * dt, &s, &c);
            ar[j] = d * c; ai[j] = d * s;
        }
        float xrv[2] = {xr.x, xr.y};
        float xiv[2] = {xi.x, xi.y};
        #pragma unroll
        for (int j = 0; j < 2; ++j) {
            float nr = ar[j] * hr[j] - ai[j] * hi[j] + xrv[j];
            float ni = ar[j] * hi[j] + ai[j] * hr[j] + xiv[j];
            hr[j] = nr; hi[j] = ni;
        }
        ntstore2(out + base,            hr[0], hr[1]);
        ntstore2(out + OUT_HALF + base, hi[0], hi[1]);
    }
}

extern "C" void kernel_launch(void* const* d_in, const int* in_sizes, int n_in,
                              void* d_out, int out_size, void* d_ws, size_t ws_size,
                              hipStream_t stream) {
    const float* nu  = (const float*)d_in[0];   // (B,L,R,C,Wf)
    const float* th  = (const float*)d_in[1];   // (B,L,R,C,Wf)
    const float* dts = (const float*)d_in[2];   // (B,L)
    const float* ur  = (const float*)d_in[3];   // (B,L,R,C,H,Wf)
    const float* ui  = (const float*)d_in[4];   // (B,L,R,C,H,Wf)
    float* out = (float*)d_out;                 // (2,B,L,R,C,H,Wf) f32

    const size_t a_elems = (size_t)BB * LL * ASLAB;          // 602112
    const bool use_ws = ws_size >= a_elems * 2 * sizeof(float);
    float* Ar = (float*)d_ws;
    float* Ai = Ar + a_elems;

    if (use_ws) {
        int na = (int)a_elems;
        a_kernel<<<(na + 255) / 256, 256, 0, stream>>>(nu, th, dts, Ar, Ai);
        scan_kernel<<<NTH2 / 256, 256, 0, stream>>>(ur, ui, Ar, Ai, out);
    } else {
        scan_kernel_nows<<<NTH2 / 256, 256, 0, stream>>>(ur, ui, nu, th, dts, out);
    }
}

// Round 7
// 77.647 us; speedup vs baseline: 1.0966x; 1.0966x over previous
//
#include <hip/hip_runtime.h>

#define BB 2
#define LL 24
#define RR 8
#define CC 32
#define HH 48
#define WF 49
#define HW (HH*WF)            // 2352
#define ASLAB (RR*CC*WF)      // 12544  (A elements per (b,l))
#define SLAB (RR*CC*HH*WF)    // 602112 (u elements per (b,l))
#define OUT_HALF (BB*LL*SLAB) // 28901376
#define NCH (BB*SLAB)         // 1204224 independent chains
#define NTHREADS (NCH/4)      // 301056 (each thread owns 4 consecutive chains)

typedef float fvec4 __attribute__((ext_vector_type(4)));

__device__ __forceinline__ void ntstore4(float* p, float a, float b, float c, float d) {
    fvec4 v = {a, b, c, d};
    __builtin_nontemporal_store(v, reinterpret_cast<fvec4*>(p));
}

// Single fused kernel: recompute A inline (fast transcendentals hide under
// the memory stream; VALUBusy was 6%), no serial a_kernel prologue, no
// A-table round trip. 4 consecutive chains/thread, float4 loads, NT stores.
__global__ __launch_bounds__(256) void scan_kernel(const float* __restrict__ ur,
                                                   const float* __restrict__ ui,
                                                   const float* __restrict__ nu,
                                                   const float* __restrict__ th,
                                                   const float* __restrict__ dts,
                                                   float* __restrict__ out) {
    int t = blockIdx.x * 256 + threadIdx.x;   // 0 .. NTHREADS-1 (exact grid)
    int c4 = t * 4;                           // first of 4 consecutive chains
    int b = c4 / SLAB;
    int rest = c4 - b * SLAB;                 // multiple of 4, < SLAB
    int rc = rest / HW;                       // r*C + c   (A group)
    int hw = rest - rc * HW;                  // h*WF + w; hw+3 < HW since HW%4==0
    int w0 = hw % WF;

    int a_off[4];
    #pragma unroll
    for (int j = 0; j < 4; ++j) {
        int wj = w0 + j; if (wj >= WF) wj -= WF;   // w wraps within same rc (h+1)
        a_off[j] = rc * WF + wj;
    }

    float hr[4] = {0.f, 0.f, 0.f, 0.f};
    float hi[4] = {0.f, 0.f, 0.f, 0.f};

    for (int l = 0; l < LL; ++l) {
        int bl = b * LL + l;
        int base = bl * SLAB + rest;          // < 28.9M, fits int
        float4 xr = *reinterpret_cast<const float4*>(ur + base);
        float4 xi = *reinterpret_cast<const float4*>(ui + base);

        int ab = bl * ASLAB;
        float dt = dts[bl];
        float ar[4], ai[4];
        #pragma unroll
        for (int j = 0; j < 4; ++j) {
            float d = __expf(-nu[ab + a_off[j]] * dt);
            float s, c;
            __sincosf(th[ab + a_off[j]] * dt, &s, &c);
            ar[j] = d * c; ai[j] = d * s;
        }

        float xrv[4] = {xr.x, xr.y, xr.z, xr.w};
        float xiv[4] = {xi.x, xi.y, xi.z, xi.w};
        #pragma unroll
        for (int j = 0; j < 4; ++j) {
            float nr = ar[j] * hr[j] - ai[j] * hi[j] + xrv[j];
            float ni = ar[j] * hi[j] + ai[j] * hr[j] + xiv[j];
            hr[j] = nr; hi[j] = ni;
        }

        ntstore4(out + base,            hr[0], hr[1], hr[2], hr[3]);
        ntstore4(out + OUT_HALF + base, hi[0], hi[1], hi[2], hi[3]);
    }
}

extern "C" void kernel_launch(void* const* d_in, const int* in_sizes, int n_in,
                              void* d_out, int out_size, void* d_ws, size_t ws_size,
                              hipStream_t stream) {
    const float* nu  = (const float*)d_in[0];   // (B,L,R,C,Wf)
    const float* th  = (const float*)d_in[1];   // (B,L,R,C,Wf)
    const float* dts = (const float*)d_in[2];   // (B,L)
    const float* ur  = (const float*)d_in[3];   // (B,L,R,C,H,Wf)
    const float* ui  = (const float*)d_in[4];   // (B,L,R,C,H,Wf)
    float* out = (float*)d_out;                 // (2,B,L,R,C,H,Wf) f32

    scan_kernel<<<NTHREADS / 256, 256, 0, stream>>>(ur, ui, nu, th, dts, out);
}